// Round 8
// baseline (713.750 us; speedup 1.0000x reference)
//
#include <hip/hip_runtime.h>
#include <stdint.h>

#pragma clang fp contract(off)

#define STEPS 50
#define BSZ 32
#define NN 64
#define DXC 8
#define DEC 5
// Output order (from scan-unpack): out0=stacked Xn (samples), out1=stacked En,
// out2=stacked Xc (pre-states), out3=stacked Ec.
#define OFF_TOTE 819200UL     // out1 base (elements)
#define OFF_OUTX 33587200UL   // out2 base
#define OFF_OUTE 34406400UL   // out3 base

// ---------------- threefry2x32 (JAX-exact, 20 rounds) ----------------
__device__ __forceinline__ uint32_t rotl32(uint32_t x, int d) {
  return (x << d) | (x >> (32 - d));
}

__device__ __forceinline__ void tf2x32(uint32_t k0, uint32_t k1,
                                       uint32_t x0, uint32_t x1,
                                       uint32_t& o0, uint32_t& o1) {
  uint32_t ks2 = k0 ^ k1 ^ 0x1BD11BDAu;
  x0 += k0; x1 += k1;
#define TF_R(r) { x0 += x1; x1 = rotl32(x1, (r)); x1 ^= x0; }
  TF_R(13) TF_R(15) TF_R(26) TF_R(6)
  x0 += k1; x1 += ks2 + 1u;
  TF_R(17) TF_R(29) TF_R(16) TF_R(24)
  x0 += ks2; x1 += k0 + 2u;
  TF_R(13) TF_R(15) TF_R(26) TF_R(6)
  x0 += k0; x1 += k1 + 3u;
  TF_R(17) TF_R(29) TF_R(16) TF_R(24)
  x0 += k1; x1 += ks2 + 4u;
  TF_R(13) TF_R(15) TF_R(26) TF_R(6)
  x0 += ks2; x1 += k0 + 5u;
#undef TF_R
  o0 = x0; o1 = x1;
}

// correctly-rounded fp32 transcendentals (f64 internal, single final rounding)
__device__ __forceinline__ float logf_cr(float x) { return (float)log((double)x); }
__device__ __forceinline__ float expf_cr(float x) { return (float)exp((double)x); }

// JAX PARTITIONABLE random_bits: bits[i] = o0 ^ o1 of cipher(key, (hi=0, lo=i));
// uniform(tiny,1) == max(uf, tiny) bit-exactly; gumbel = -log(-log(u)) fp32.
__device__ __attribute__((noinline)) float gumbel_part(uint32_t k0, uint32_t k1,
                                                       uint32_t idx) {
  uint32_t o0, o1;
  tf2x32(k0, k1, 0u, idx, o0, o1);
  uint32_t bits = o0 ^ o1;
  float uf = __uint_as_float((bits >> 9) | 0x3f800000u) - 1.0f;
  float u = fmaxf(uf, 1.1754943508222875e-38f);
  return -logf_cr(-logf_cr(u));
}

// dtype auto-detect on X's first 32 bytes: f32 one-hot row -> exactly one u16
// == 0x3F80; bf16 -> rows 0..1 -> exactly two.
__device__ __forceinline__ bool detect_bf16(const void* X) {
  const uint16_t* u = (const uint16_t*)X;
  int c = 0;
  for (int i = 0; i < 16; ++i) c += (u[i] == 0x3F80u);
  return c >= 2;
}

__device__ __forceinline__ float ld(const void* p, size_t i, bool bf) {
  if (bf) return __uint_as_float(((uint32_t)((const uint16_t*)p)[i]) << 16);
  return ((const float*)p)[i];
}
__device__ __forceinline__ void st(void* p, size_t i, bool bf, float v) {
  if (bf) ((uint16_t*)p)[i] = (uint16_t)(__float_as_uint(v) >> 16);  // 0/1 exact
  else ((float*)p)[i] = v;
}

// mask layouts: u8 bool (byte1==1: node (0,1) always valid since lengths>=32),
// bf16 (byte1==0x3F), else 4-byte words (i32 0/1 or f32 bit pattern).
__device__ __forceinline__ bool read_mask(const void* mp, int idx) {
  const uint8_t* m8 = (const uint8_t*)mp;
  uint8_t b1 = m8[1];
  if (b1 == 0) return ((const uint32_t*)mp)[idx] != 0;
  if (b1 == 0x3F) return ((const uint16_t*)mp)[idx] != 0;
  return m8[idx] != 0;
}

// fp32 pred pipeline for current class c, every op fp32 in reference order,
// exp/log correctly rounded:
// softmax(W[c,:]) -> *gamma -> zero c -> clamped remainder at c -> norm -> log
template <int D>
__device__ void fill_logp(const void* __restrict__ W, bool bf, float gamma,
                          int c, float* __restrict__ out) {
  float t[D];
  for (int d = 0; d < D; ++d) t[d] = ld(W, c * D + d, bf);  // one-hot @ W exact
  float m = t[0];
  for (int d = 1; d < D; ++d) m = fmaxf(m, t[d]);
  float u[D];
  for (int d = 0; d < D; ++d) u[d] = expf_cr(t[d] - m);
  float s = 0.0f;
  for (int d = 0; d < D; ++d) s += u[d];
  float p[D];
  for (int d = 0; d < D; ++d) p[d] = (u[d] / s) * gamma;
  p[c] = 0.0f;
  float s1 = 0.0f;
  for (int d = 0; d < D; ++d) s1 += p[d];
  float r = fmaxf(1.0f - s1, 0.0f);
  p[c] = r;
  float s2 = 0.0f;
  for (int d = 0; d < D; ++d) s2 += p[d];
  for (int d = 0; d < D; ++d) out[d] = logf_cr(p[d] / s2);
}

// blocks [0,512): one thread per (b,i,j); mirror threads recompute the
// canonical (lo,hi) chain (counter-based PRNG makes this exact) so all global
// writes stay coalesced. blocks [512,520): one thread per (b,i) node.
__global__ __launch_bounds__(256) void lang_kernel(
    const void* __restrict__ X, const void* __restrict__ E,
    const void* __restrict__ M, const void* __restrict__ gammas,
    const void* __restrict__ Wx, const void* __restrict__ We,
    void* __restrict__ out) {
  __shared__ uint32_t skeys[STEPS * 2];
  __shared__ float stab[STEPS * DXC * DXC];
  const bool edge_blk = blockIdx.x < 512;
  const int t = threadIdx.x;
  const bool bf = detect_bf16(X);

  if (t < STEPS) {
    // fold_in(key(42),k) = cipher((0,42),(0,k)); foldlike split:
    // subkey_j = both words of cipher(folded,(0,j)); kx=sub0, ke=sub1.
    uint32_t f0, f1, a0, a1;
    tf2x32(0u, 42u, 0u, (uint32_t)t, f0, f1);
    tf2x32(f0, f1, 0u, edge_blk ? 1u : 0u, a0, a1);
    skeys[2 * t] = a0; skeys[2 * t + 1] = a1;
  }
  if (edge_blk) {
    for (int task = t; task < STEPS * DEC; task += 256) {
      int k = task / DEC, c = task % DEC;
      fill_logp<DEC>(We, bf, ld(gammas, k, bf), c, &stab[(k * DEC + c) * DEC]);
    }
  } else {
    for (int task = t; task < STEPS * DXC; task += 256) {
      int k = task / DXC, c = task % DXC;
      fill_logp<DXC>(Wx, bf, ld(gammas, k, bf), c, &stab[(k * DXC + c) * DXC]);
    }
  }
  __syncthreads();

  if (edge_blk) {
    int tid = blockIdx.x * 256 + threadIdx.x;  // (b,i,j)
    int b = tid >> 12, rem = tid & 4095, i = rem >> 6, j = rem & 63;
    bool valid = (i != j) && read_mask(M, b * NN + i) && read_mask(M, b * NN + j);
    int lo = i < j ? i : j, hi = i < j ? j : i;
    int cur = 0;
    if (valid) {
      size_t crow = (((size_t)(b * NN + lo)) * NN + hi) * DEC;
      float bst = ld(E, crow, bf);
      for (int d = 1; d < DEC; ++d) {
        float v = ld(E, crow + d, bf);
        if (v > bst) { bst = v; cur = d; }
      }
    }
    uint32_t base = (uint32_t)((((b * NN) + lo) * NN + hi) * DEC);
#pragma clang loop unroll(disable)
    for (int k = 0; k < STEPS; ++k) {
      size_t tp = ((((size_t)b * STEPS + k) * NN + i) * NN + j) * DEC;
      // out3 (stacked Ec, pre-state): k=0 -> raw input E row (incl. diagonal /
      // invalid); k>=1 -> previous masked sample one-hot.
      if (k == 0) {
        for (int d = 0; d < DEC; ++d)
          st(out, OFF_OUTE + tp + d, bf, ld(E, (size_t)tid * DEC + d, bf));
      } else {
        for (int d = 0; d < DEC; ++d)
          st(out, OFF_OUTE + tp + d, bf, (valid && d == cur) ? 1.0f : 0.0f);
      }
      int nxt = 0;
      if (valid) {
        const float* le = stab + (k * DEC + cur) * DEC;
        uint32_t k0 = skeys[2 * k], k1 = skeys[2 * k + 1];
        float bst = -3.0e38f;
        for (int d = 0; d < DEC; ++d) {
          float s = le[d] + gumbel_part(k0, k1, base + (uint32_t)d);  // fp32 add
          if (s > bst) { bst = s; nxt = d; }  // first-max, like jnp.argmax
        }
      }
      // out1 (stacked En, post-sample): masked one-hot of this step's sample.
      for (int d = 0; d < DEC; ++d)
        st(out, OFF_TOTE + tp + d, bf, (valid && d == nxt) ? 1.0f : 0.0f);
      cur = nxt;
    }
  } else {
    int tid = (int)(blockIdx.x - 512) * 256 + threadIdx.x;  // (b,i)
    if (tid >= BSZ * NN) return;
    int b = tid >> 6, i = tid & 63;
    bool valid = read_mask(M, tid);
    int cur = 0;
    {
      float bst = ld(X, (size_t)tid * DXC, bf);
      for (int d = 1; d < DXC; ++d) {
        float v = ld(X, (size_t)tid * DXC + d, bf);
        if (v > bst) { bst = v; cur = d; }
      }
    }
    uint32_t base = (uint32_t)(tid * DXC);
#pragma clang loop unroll(disable)
    for (int k = 0; k < STEPS; ++k) {
      size_t tp = (((size_t)b * STEPS + k) * NN + i) * DXC;
      // out2 (stacked Xc, pre-state): k=0 -> raw input X row; k>=1 -> previous
      // masked sample one-hot.
      if (k == 0) {
        for (int d = 0; d < DXC; ++d)
          st(out, OFF_OUTX + tp + d, bf, ld(X, (size_t)tid * DXC + d, bf));
      } else {
        for (int d = 0; d < DXC; ++d)
          st(out, OFF_OUTX + tp + d, bf, (valid && d == cur) ? 1.0f : 0.0f);
      }
      int nxt = 0;
      if (valid) {
        const float* lx = stab + (k * DXC + cur) * DXC;
        uint32_t k0 = skeys[2 * k], k1 = skeys[2 * k + 1];
        float bst = -3.0e38f;
        for (int d = 0; d < DXC; ++d) {
          float s = lx[d] + gumbel_part(k0, k1, base + (uint32_t)d);
          if (s > bst) { bst = s; nxt = d; }
        }
      }
      // out0 (stacked Xn, post-sample): masked one-hot of this step's sample.
      for (int d = 0; d < DXC; ++d)
        st(out, tp + d, bf, (valid && d == nxt) ? 1.0f : 0.0f);
      cur = nxt;
    }
  }
}

extern "C" void kernel_launch(void* const* d_in, const int* in_sizes, int n_in,
                              void* d_out, int out_size, void* d_ws, size_t ws_size,
                              hipStream_t stream) {
  (void)out_size; (void)d_ws; (void)ws_size;
  // Robust input binding: element counts are all distinct
  // (X 16384, E 655360, mask 2048, gammas 50, Wx 64, We 25).
  const void* X = d_in[0];
  const void* E = d_in[1];
  const void* M = d_in[2];
  const void* G = d_in[3];
  const void* Wx = d_in[4];
  const void* We = d_in[5];
  for (int i = 0; i < n_in && i < 6; ++i) {
    switch (in_sizes[i]) {
      case 16384:  X = d_in[i]; break;
      case 655360: E = d_in[i]; break;
      case 2048:   M = d_in[i]; break;
      case 50:     G = d_in[i]; break;
      case 64:     Wx = d_in[i]; break;
      case 25:     We = d_in[i]; break;
      default: break;
    }
  }
  hipLaunchKernelGGL(lang_kernel, dim3(520), dim3(256), 0, stream,
                     X, E, M, G, Wx, We, d_out);
}

// Round 9
// 553.513 us; speedup vs baseline: 1.2895x; 1.2895x over previous
//
#include <hip/hip_runtime.h>
#include <stdint.h>

#pragma clang fp contract(off)

#define STEPS 50
#define BSZ 32
#define NN 64
#define DXC 8
#define DEC 5
// Output order (scan-unpack): out0=stacked Xn, out1=stacked En,
// out2=stacked Xc, out3=stacked Ec.
#define OFF_TOTE 819200UL     // out1 base (elements)
#define OFF_OUTX 33587200UL   // out2 base
#define OFF_OUTE 34406400UL   // out3 base

#define NPAIR 2016            // upper-tri pairs per batch
#define EDGE_CHAINS 64512     // 32*2016
#define NODE_CHAINS 2048      // 32*64
// ws layout (bytes)
#define WS_KEYS 0UL                                  // u32[200]: kx[0..99], ke[100..199]
#define WS_GE   1024UL                               // f32[64512*250]
#define WS_GN   (1024UL + 64512000UL)                // f32[2048*400]
#define WS_S    (1024UL + 64512000UL + 3276800UL)    // u8[66560*52]
#define WS_NEED (1024UL + 64512000UL + 3276800UL + 3461120UL)

// ---------------- threefry2x32 (JAX-exact, 20 rounds) ----------------
__device__ __forceinline__ uint32_t rotl32(uint32_t x, int d) {
  return (x << d) | (x >> (32 - d));
}

__device__ __forceinline__ void tf2x32(uint32_t k0, uint32_t k1,
                                       uint32_t x0, uint32_t x1,
                                       uint32_t& o0, uint32_t& o1) {
  uint32_t ks2 = k0 ^ k1 ^ 0x1BD11BDAu;
  x0 += k0; x1 += k1;
#define TF_R(r) { x0 += x1; x1 = rotl32(x1, (r)); x1 ^= x0; }
  TF_R(13) TF_R(15) TF_R(26) TF_R(6)
  x0 += k1; x1 += ks2 + 1u;
  TF_R(17) TF_R(29) TF_R(16) TF_R(24)
  x0 += ks2; x1 += k0 + 2u;
  TF_R(13) TF_R(15) TF_R(26) TF_R(6)
  x0 += k0; x1 += k1 + 3u;
  TF_R(17) TF_R(29) TF_R(16) TF_R(24)
  x0 += k1; x1 += ks2 + 4u;
  TF_R(13) TF_R(15) TF_R(26) TF_R(6)
  x0 += ks2; x1 += k0 + 5u;
#undef TF_R
  o0 = x0; o1 = x1;
}

// correctly-rounded fp32 transcendentals (f64 internal, single final rounding)
__device__ __forceinline__ float logf_cr(float x) { return (float)log((double)x); }
__device__ __forceinline__ float expf_cr(float x) { return (float)exp((double)x); }

// JAX PARTITIONABLE random_bits: bits[i] = o0 ^ o1 of cipher(key, (hi=0, lo=i));
// uniform(tiny,1) == max(uf, tiny) bit-exactly; gumbel = -log(-log(u)) fp32.
__device__ __attribute__((noinline)) float gumbel_part(uint32_t k0, uint32_t k1,
                                                       uint32_t idx) {
  uint32_t o0, o1;
  tf2x32(k0, k1, 0u, idx, o0, o1);
  uint32_t bits = o0 ^ o1;
  float uf = __uint_as_float((bits >> 9) | 0x3f800000u) - 1.0f;
  float u = fmaxf(uf, 1.1754943508222875e-38f);
  return -logf_cr(-logf_cr(u));
}

// dtype auto-detect on X's first 32 bytes: f32 one-hot row -> exactly one u16
// == 0x3F80; bf16 -> rows 0..1 -> exactly two.
__device__ __forceinline__ bool detect_bf16(const void* X) {
  const uint16_t* u = (const uint16_t*)X;
  int c = 0;
  for (int i = 0; i < 16; ++i) c += (u[i] == 0x3F80u);
  return c >= 2;
}

__device__ __forceinline__ float ld(const void* p, size_t i, bool bf) {
  if (bf) return __uint_as_float(((uint32_t)((const uint16_t*)p)[i]) << 16);
  return ((const float*)p)[i];
}
__device__ __forceinline__ void st(void* p, size_t i, bool bf, float v) {
  if (bf) ((uint16_t*)p)[i] = (uint16_t)(__float_as_uint(v) >> 16);  // 0/1 exact
  else ((float*)p)[i] = v;
}

// mask layouts: u8 bool (byte1==1: node (0,1) always valid since lengths>=32),
// bf16 (byte1==0x3F), else 4-byte words (i32 0/1 or f32 bit pattern).
__device__ __forceinline__ bool read_mask(const void* mp, int idx) {
  const uint8_t* m8 = (const uint8_t*)mp;
  uint8_t b1 = m8[1];
  if (b1 == 0) return ((const uint32_t*)mp)[idx] != 0;
  if (b1 == 0x3F) return ((const uint16_t*)mp)[idx] != 0;
  return m8[idx] != 0;
}

// fp32 pred pipeline for current class c, every op fp32 in reference order,
// exp/log correctly rounded.
template <int D>
__device__ void fill_logp(const void* __restrict__ W, bool bf, float gamma,
                          int c, float* __restrict__ out) {
  float t[D];
  for (int d = 0; d < D; ++d) t[d] = ld(W, c * D + d, bf);
  float m = t[0];
  for (int d = 1; d < D; ++d) m = fmaxf(m, t[d]);
  float u[D];
  for (int d = 0; d < D; ++d) u[d] = expf_cr(t[d] - m);
  float s = 0.0f;
  for (int d = 0; d < D; ++d) s += u[d];
  float p[D];
  for (int d = 0; d < D; ++d) p[d] = (u[d] / s) * gamma;
  p[c] = 0.0f;
  float s1 = 0.0f;
  for (int d = 0; d < D; ++d) s1 += p[d];
  float r = fmaxf(1.0f - s1, 0.0f);
  p[c] = r;
  float s2 = 0.0f;
  for (int d = 0; d < D; ++d) s2 += p[d];
  for (int d = 0; d < D; ++d) out[d] = logf_cr(p[d] / s2);
}

// triangular decode: q in [0,2016) -> (lo,hi), row lo has 63-lo entries
__device__ __forceinline__ void pair_decode(int q, int& lo, int& hi) {
  lo = 0; int rem = q;
  while (rem >= 63 - lo) { rem -= 63 - lo; lo++; }
  hi = lo + 1 + rem;
}

// ---------------- K0: per-step PRNG subkeys ----------------
__global__ void key_kernel(uint8_t* __restrict__ ws) {
  int t = threadIdx.x;
  uint32_t* wk = (uint32_t*)(ws + WS_KEYS);
  if (t < STEPS) {
    uint32_t f0, f1, a0, a1;
    tf2x32(0u, 42u, 0u, (uint32_t)t, f0, f1);
    tf2x32(f0, f1, 0u, 0u, a0, a1);  // kx
    wk[2 * t] = a0; wk[2 * t + 1] = a1;
    tf2x32(f0, f1, 0u, 1u, a0, a1);  // ke
    wk[100 + 2 * t] = a0; wk[101 + 2 * t] = a1;
  }
}

// ---------------- K1: all gumbels, massively parallel ----------------
// blocks [0,64512): one per canonical valid pair (250 gumbels by 250 threads)
// blocks [64512,66560): one per valid node (400 gumbels, 2 rounds)
__global__ __launch_bounds__(256) void gumbel_kernel(const void* __restrict__ M,
                                                     uint8_t* __restrict__ ws) {
  const uint32_t* keys = (const uint32_t*)(ws + WS_KEYS);
  int blk = blockIdx.x, tid = threadIdx.x;
  if (blk < EDGE_CHAINS) {
    int b = blk / NPAIR, q = blk % NPAIR, lo, hi;
    pair_decode(q, lo, hi);
    if (!(read_mask(M, b * NN + lo) && read_mask(M, b * NN + hi))) return;
    if (tid < STEPS * DEC) {
      int k = tid / DEC, d = tid % DEC;
      uint32_t ctr = (uint32_t)(((b * NN + lo) * NN + hi) * DEC + d);
      ((float*)(ws + WS_GE))[(size_t)blk * 250 + tid] =
          gumbel_part(keys[100 + 2 * k], keys[101 + 2 * k], ctr);
    }
  } else {
    int node = blk - EDGE_CHAINS;
    if (!read_mask(M, node)) return;
    for (int r = 0; r < 2; ++r) {
      int slot = r * 256 + tid;
      if (slot < STEPS * DXC) {
        int k = slot / DXC, d = slot % DXC;
        uint32_t ctr = (uint32_t)(node * DXC + d);
        ((float*)(ws + WS_GN))[(size_t)node * 400 + slot] =
            gumbel_part(keys[2 * k], keys[2 * k + 1], ctr);
      }
    }
  }
}

// ---------------- K2: sequential argmax chains -> sample bytes ----------------
// blocks [0,252): edge chains (thread per canonical pair); [252,260): nodes.
__global__ __launch_bounds__(256) void chain_kernel(
    const void* __restrict__ X, const void* __restrict__ E,
    const void* __restrict__ M, const void* __restrict__ gammas,
    const void* __restrict__ Wx, const void* __restrict__ We,
    uint8_t* __restrict__ ws) {
  __shared__ float stab[STEPS * DXC * DXC];
  const bool edge_blk = blockIdx.x < 252;
  const int t = threadIdx.x;
  const bool bf = detect_bf16(X);

  if (edge_blk) {
    for (int task = t; task < STEPS * DEC; task += 256)
      fill_logp<DEC>(We, bf, ld(gammas, task / DEC, bf), task % DEC,
                     &stab[task * DEC]);
  } else {
    for (int task = t; task < STEPS * DXC; task += 256)
      fill_logp<DXC>(Wx, bf, ld(gammas, task / DXC, bf), task % DXC,
                     &stab[task * DXC]);
  }
  __syncthreads();

  if (edge_blk) {
    int chain = blockIdx.x * 256 + t;  // < 64512
    int b = chain / NPAIR, q = chain % NPAIR, lo, hi;
    pair_decode(q, lo, hi);
    if (!(read_mask(M, b * NN + lo) && read_mask(M, b * NN + hi))) return;
    size_t crow = (((size_t)(b * NN + lo)) * NN + hi) * DEC;
    int cur = 0;
    float bst = ld(E, crow, bf);
    for (int d = 1; d < DEC; ++d) {
      float v = ld(E, crow + d, bf);
      if (v > bst) { bst = v; cur = d; }
    }
    const float* g = (const float*)(ws + WS_GE) + (size_t)chain * 250;
    uint8_t* sp = ws + WS_S + (size_t)chain * 52;
    for (int k = 0; k < STEPS; ++k) {
      const float* le = stab + (k * DEC + cur) * DEC;
      const float* gk = g + k * DEC;
      float bs = -3.0e38f; int nxt = 0;
      for (int d = 0; d < DEC; ++d) {
        float s = le[d] + gk[d];
        if (s > bs) { bs = s; nxt = d; }  // first-max, like jnp.argmax
      }
      sp[k] = (uint8_t)nxt;
      cur = nxt;
    }
  } else {
    int node = (int)(blockIdx.x - 252) * 256 + t;  // < 2048
    if (!read_mask(M, node)) return;
    int cur = 0;
    float bst = ld(X, (size_t)node * DXC, bf);
    for (int d = 1; d < DXC; ++d) {
      float v = ld(X, (size_t)node * DXC + d, bf);
      if (v > bst) { bst = v; cur = d; }
    }
    const float* g = (const float*)(ws + WS_GN) + (size_t)node * 400;
    uint8_t* sp = ws + WS_S + (size_t)(EDGE_CHAINS + node) * 52;
    for (int k = 0; k < STEPS; ++k) {
      const float* le = stab + (k * DXC + cur) * DXC;
      const float* gk = g + k * DXC;
      float bs = -3.0e38f; int nxt = 0;
      for (int d = 0; d < DXC; ++d) {
        float s = le[d] + gk[d];
        if (s > bs) { bs = s; nxt = d; }
      }
      sp[k] = (uint8_t)nxt;
      cur = nxt;
    }
  }
}

__device__ __forceinline__ int sbyte(const uint32_t* s13, int k) {
  return (int)((s13[k >> 2] >> ((k & 3) * 8)) & 0xFFu);
}

// ---------------- K3: pure coalesced writer ----------------
// blocks [0,512): thread per (b,i,j); [512,520): thread per node.
__global__ __launch_bounds__(256) void write_kernel(
    const void* __restrict__ X, const void* __restrict__ E,
    const void* __restrict__ M, const uint8_t* __restrict__ ws,
    void* __restrict__ out) {
  const bool edge_blk = blockIdx.x < 512;
  const bool bf = detect_bf16(X);
  if (edge_blk) {
    int tid = blockIdx.x * 256 + threadIdx.x;
    int b = tid >> 12, rem = tid & 4095, i = rem >> 6, j = rem & 63;
    bool valid = (i != j) && read_mask(M, b * NN + i) && read_mask(M, b * NN + j);
    int lo = i < j ? i : j, hi = i < j ? j : i;
    uint32_t s13[13] = {0};
    if (valid) {
      int q = 63 * lo - lo * (lo - 1) / 2 + (hi - lo - 1);
      const uint32_t* sp =
          (const uint32_t*)(ws + WS_S + (size_t)(b * NPAIR + q) * 52);
      for (int w = 0; w < 13; ++w) s13[w] = sp[w];
    }
    for (int k = 0; k < STEPS; ++k) {
      size_t tp = ((((size_t)b * STEPS + k) * NN + i) * NN + j) * DEC;
      // out3 (pre-state Ec): k=0 raw input row; k>=1 one-hot of s[k-1]
      if (k == 0) {
        for (int d = 0; d < DEC; ++d)
          st(out, OFF_OUTE + tp + d, bf, ld(E, (size_t)tid * DEC + d, bf));
      } else {
        int pre = sbyte(s13, k - 1);
        for (int d = 0; d < DEC; ++d)
          st(out, OFF_OUTE + tp + d, bf, (valid && d == pre) ? 1.0f : 0.0f);
      }
      // out1 (post-sample En): one-hot of s[k]
      int nxt = sbyte(s13, k);
      for (int d = 0; d < DEC; ++d)
        st(out, OFF_TOTE + tp + d, bf, (valid && d == nxt) ? 1.0f : 0.0f);
    }
  } else {
    int node = (int)(blockIdx.x - 512) * 256 + threadIdx.x;  // < 2048
    bool valid = read_mask(M, node);
    int b = node >> 6, i = node & 63;
    uint32_t s13[13] = {0};
    if (valid) {
      const uint32_t* sp =
          (const uint32_t*)(ws + WS_S + (size_t)(EDGE_CHAINS + node) * 52);
      for (int w = 0; w < 13; ++w) s13[w] = sp[w];
    }
    for (int k = 0; k < STEPS; ++k) {
      size_t tp = (((size_t)b * STEPS + k) * NN + i) * DXC;
      if (k == 0) {
        for (int d = 0; d < DXC; ++d)
          st(out, OFF_OUTX + tp + d, bf, ld(X, (size_t)node * DXC + d, bf));
      } else {
        int pre = sbyte(s13, k - 1);
        for (int d = 0; d < DXC; ++d)
          st(out, OFF_OUTX + tp + d, bf, (valid && d == pre) ? 1.0f : 0.0f);
      }
      int nxt = sbyte(s13, k);
      for (int d = 0; d < DXC; ++d)
        st(out, tp + d, bf, (valid && d == nxt) ? 1.0f : 0.0f);
    }
  }
}

// ---------------- fallback: r8's passing single kernel (verbatim) ----------
__global__ __launch_bounds__(256) void lang_kernel(
    const void* __restrict__ X, const void* __restrict__ E,
    const void* __restrict__ M, const void* __restrict__ gammas,
    const void* __restrict__ Wx, const void* __restrict__ We,
    void* __restrict__ out) {
  __shared__ uint32_t skeys[STEPS * 2];
  __shared__ float stab[STEPS * DXC * DXC];
  const bool edge_blk = blockIdx.x < 512;
  const int t = threadIdx.x;
  const bool bf = detect_bf16(X);

  if (t < STEPS) {
    uint32_t f0, f1, a0, a1;
    tf2x32(0u, 42u, 0u, (uint32_t)t, f0, f1);
    tf2x32(f0, f1, 0u, edge_blk ? 1u : 0u, a0, a1);
    skeys[2 * t] = a0; skeys[2 * t + 1] = a1;
  }
  if (edge_blk) {
    for (int task = t; task < STEPS * DEC; task += 256) {
      int k = task / DEC, c = task % DEC;
      fill_logp<DEC>(We, bf, ld(gammas, k, bf), c, &stab[(k * DEC + c) * DEC]);
    }
  } else {
    for (int task = t; task < STEPS * DXC; task += 256) {
      int k = task / DXC, c = task % DXC;
      fill_logp<DXC>(Wx, bf, ld(gammas, k, bf), c, &stab[(k * DXC + c) * DXC]);
    }
  }
  __syncthreads();

  if (edge_blk) {
    int tid = blockIdx.x * 256 + threadIdx.x;
    int b = tid >> 12, rem = tid & 4095, i = rem >> 6, j = rem & 63;
    bool valid = (i != j) && read_mask(M, b * NN + i) && read_mask(M, b * NN + j);
    int lo = i < j ? i : j, hi = i < j ? j : i;
    int cur = 0;
    if (valid) {
      size_t crow = (((size_t)(b * NN + lo)) * NN + hi) * DEC;
      float bst = ld(E, crow, bf);
      for (int d = 1; d < DEC; ++d) {
        float v = ld(E, crow + d, bf);
        if (v > bst) { bst = v; cur = d; }
      }
    }
    uint32_t base = (uint32_t)((((b * NN) + lo) * NN + hi) * DEC);
#pragma clang loop unroll(disable)
    for (int k = 0; k < STEPS; ++k) {
      size_t tp = ((((size_t)b * STEPS + k) * NN + i) * NN + j) * DEC;
      if (k == 0) {
        for (int d = 0; d < DEC; ++d)
          st(out, OFF_OUTE + tp + d, bf, ld(E, (size_t)tid * DEC + d, bf));
      } else {
        for (int d = 0; d < DEC; ++d)
          st(out, OFF_OUTE + tp + d, bf, (valid && d == cur) ? 1.0f : 0.0f);
      }
      int nxt = 0;
      if (valid) {
        const float* le = stab + (k * DEC + cur) * DEC;
        uint32_t k0 = skeys[2 * k], k1 = skeys[2 * k + 1];
        float bst = -3.0e38f;
        for (int d = 0; d < DEC; ++d) {
          float s = le[d] + gumbel_part(k0, k1, base + (uint32_t)d);
          if (s > bst) { bst = s; nxt = d; }
        }
      }
      for (int d = 0; d < DEC; ++d)
        st(out, OFF_TOTE + tp + d, bf, (valid && d == nxt) ? 1.0f : 0.0f);
      cur = nxt;
    }
  } else {
    int tid = (int)(blockIdx.x - 512) * 256 + threadIdx.x;
    if (tid >= BSZ * NN) return;
    int b = tid >> 6, i = tid & 63;
    bool valid = read_mask(M, tid);
    int cur = 0;
    {
      float bst = ld(X, (size_t)tid * DXC, bf);
      for (int d = 1; d < DXC; ++d) {
        float v = ld(X, (size_t)tid * DXC + d, bf);
        if (v > bst) { bst = v; cur = d; }
      }
    }
    uint32_t base = (uint32_t)(tid * DXC);
#pragma clang loop unroll(disable)
    for (int k = 0; k < STEPS; ++k) {
      size_t tp = (((size_t)b * STEPS + k) * NN + i) * DXC;
      if (k == 0) {
        for (int d = 0; d < DXC; ++d)
          st(out, OFF_OUTX + tp + d, bf, ld(X, (size_t)tid * DXC + d, bf));
      } else {
        for (int d = 0; d < DXC; ++d)
          st(out, OFF_OUTX + tp + d, bf, (valid && d == cur) ? 1.0f : 0.0f);
      }
      int nxt = 0;
      if (valid) {
        const float* lx = stab + (k * DXC + cur) * DXC;
        uint32_t k0 = skeys[2 * k], k1 = skeys[2 * k + 1];
        float bst = -3.0e38f;
        for (int d = 0; d < DXC; ++d) {
          float s = lx[d] + gumbel_part(k0, k1, base + (uint32_t)d);
          if (s > bst) { bst = s; nxt = d; }
        }
      }
      for (int d = 0; d < DXC; ++d)
        st(out, tp + d, bf, (valid && d == nxt) ? 1.0f : 0.0f);
      cur = nxt;
    }
  }
}

extern "C" void kernel_launch(void* const* d_in, const int* in_sizes, int n_in,
                              void* d_out, int out_size, void* d_ws, size_t ws_size,
                              hipStream_t stream) {
  (void)out_size;
  // Robust input binding: element counts are all distinct
  // (X 16384, E 655360, mask 2048, gammas 50, Wx 64, We 25).
  const void* X = d_in[0];
  const void* E = d_in[1];
  const void* M = d_in[2];
  const void* G = d_in[3];
  const void* Wx = d_in[4];
  const void* We = d_in[5];
  for (int i = 0; i < n_in && i < 6; ++i) {
    switch (in_sizes[i]) {
      case 16384:  X = d_in[i]; break;
      case 655360: E = d_in[i]; break;
      case 2048:   M = d_in[i]; break;
      case 50:     G = d_in[i]; break;
      case 64:     Wx = d_in[i]; break;
      case 25:     We = d_in[i]; break;
      default: break;
    }
  }
  if (ws_size >= WS_NEED) {
    uint8_t* ws = (uint8_t*)d_ws;
    hipLaunchKernelGGL(key_kernel, dim3(1), dim3(64), 0, stream, ws);
    hipLaunchKernelGGL(gumbel_kernel, dim3(EDGE_CHAINS + NODE_CHAINS), dim3(256),
                       0, stream, M, ws);
    hipLaunchKernelGGL(chain_kernel, dim3(260), dim3(256), 0, stream,
                       X, E, M, G, Wx, We, ws);
    hipLaunchKernelGGL(write_kernel, dim3(520), dim3(256), 0, stream,
                       X, E, M, ws, d_out);
  } else {
    hipLaunchKernelGGL(lang_kernel, dim3(520), dim3(256), 0, stream,
                       X, E, M, G, Wx, We, d_out);
  }
}

// Round 10
// 436.326 us; speedup vs baseline: 1.6358x; 1.2686x over previous
//
#include <hip/hip_runtime.h>
#include <stdint.h>

#pragma clang fp contract(off)

#define STEPS 50
#define BSZ 32
#define NN 64
#define DXC 8
#define DEC 5
// Output order (scan-unpack): out0=stacked Xn, out1=stacked En,
// out2=stacked Xc, out3=stacked Ec.
#define OFF_TOTE 819200UL     // out1 base (elements)
#define OFF_OUTX 33587200UL   // out2 base
#define OFF_OUTE 34406400UL   // out3 base

#define NPAIR 2016            // upper-tri pairs per batch
#define EDGE_CHAINS 64512     // 32*2016
#define NODE_CHAINS 2048      // 32*64
#define EBLK 16128            // edge gumbel blocks (4 chains each)
// ws layout (bytes). Fits under r9's proven 71,250,944 B gate.
#define WS_KEYS 0UL                 // u32[256]: kx[0..99], ke[100..199], cnt[200]
#define WS_CL   1024UL              // u16[64512] compacted valid chain ids
#define WS_GE   130048UL            // f32[64512*250]
#define WS_GN   64642048UL          // f32[2048*400]
#define WS_S2E  67918848UL          // u8[1600*2016]  samples, slab-major
#define WS_S2N  71144448UL          // u8[1600*64]
#define WS_NEED 71246848UL

// ---------------- threefry2x32 (JAX-exact, 20 rounds) ----------------
__device__ __forceinline__ uint32_t rotl32(uint32_t x, int d) {
  return (x << d) | (x >> (32 - d));
}

__device__ __forceinline__ void tf2x32(uint32_t k0, uint32_t k1,
                                       uint32_t x0, uint32_t x1,
                                       uint32_t& o0, uint32_t& o1) {
  uint32_t ks2 = k0 ^ k1 ^ 0x1BD11BDAu;
  x0 += k0; x1 += k1;
#define TF_R(r) { x0 += x1; x1 = rotl32(x1, (r)); x1 ^= x0; }
  TF_R(13) TF_R(15) TF_R(26) TF_R(6)
  x0 += k1; x1 += ks2 + 1u;
  TF_R(17) TF_R(29) TF_R(16) TF_R(24)
  x0 += ks2; x1 += k0 + 2u;
  TF_R(13) TF_R(15) TF_R(26) TF_R(6)
  x0 += k0; x1 += k1 + 3u;
  TF_R(17) TF_R(29) TF_R(16) TF_R(24)
  x0 += k1; x1 += ks2 + 4u;
  TF_R(13) TF_R(15) TF_R(26) TF_R(6)
  x0 += ks2; x1 += k0 + 5u;
#undef TF_R
  o0 = x0; o1 = x1;
}

__device__ __forceinline__ float logf_cr(float x) { return (float)log((double)x); }
__device__ __forceinline__ float expf_cr(float x) { return (float)exp((double)x); }

// JAX PARTITIONABLE random_bits: bits[i] = o0 ^ o1 of cipher(key, (hi=0, lo=i));
// uniform(tiny,1) == max(uf, tiny) bit-exactly; gumbel = -log(-log(u)) fp32 CR.
__device__ __forceinline__ float gumbel_inl(uint32_t k0, uint32_t k1,
                                            uint32_t idx) {
  uint32_t o0, o1;
  tf2x32(k0, k1, 0u, idx, o0, o1);
  uint32_t bits = o0 ^ o1;
  float uf = __uint_as_float((bits >> 9) | 0x3f800000u) - 1.0f;
  float u = fmaxf(uf, 1.1754943508222875e-38f);
  return -logf_cr(-logf_cr(u));
}
// noinline wrapper for the single-kernel fallback (compile-time control)
__device__ __attribute__((noinline)) float gumbel_part(uint32_t k0, uint32_t k1,
                                                       uint32_t idx) {
  return gumbel_inl(k0, k1, idx);
}

// dtype auto-detect on X's first 32 bytes.
__device__ __forceinline__ bool detect_bf16(const void* X) {
  const uint16_t* u = (const uint16_t*)X;
  int c = 0;
  for (int i = 0; i < 16; ++i) c += (u[i] == 0x3F80u);
  return c >= 2;
}

__device__ __forceinline__ float ld(const void* p, size_t i, bool bf) {
  if (bf) return __uint_as_float(((uint32_t)((const uint16_t*)p)[i]) << 16);
  return ((const float*)p)[i];
}
__device__ __forceinline__ void st(void* p, size_t i, bool bf, float v) {
  if (bf) ((uint16_t*)p)[i] = (uint16_t)(__float_as_uint(v) >> 16);
  else ((float*)p)[i] = v;
}
// vector store of 4 consecutive elements (element index e4 = idx/4)
__device__ __forceinline__ void stv4(void* p, size_t e4, bool bf,
                                     float a, float b, float c, float d) {
  if (!bf) {
    float4 v; v.x = a; v.y = b; v.z = c; v.w = d;
    ((float4*)p)[e4] = v;
  } else {
    ushort4 v;
    v.x = (uint16_t)(__float_as_uint(a) >> 16);
    v.y = (uint16_t)(__float_as_uint(b) >> 16);
    v.z = (uint16_t)(__float_as_uint(c) >> 16);
    v.w = (uint16_t)(__float_as_uint(d) >> 16);
    ((ushort4*)p)[e4] = v;
  }
}
// raw bit-copy of 4 consecutive elements
__device__ __forceinline__ void cpy4(void* dst, const void* src, size_t de4,
                                     size_t se4, bool bf) {
  if (!bf) ((float4*)dst)[de4] = ((const float4*)src)[se4];
  else ((uint2*)dst)[de4] = ((const uint2*)src)[se4];
}

__device__ __forceinline__ bool read_mask(const void* mp, int idx) {
  const uint8_t* m8 = (const uint8_t*)mp;
  uint8_t b1 = m8[1];
  if (b1 == 0) return ((const uint32_t*)mp)[idx] != 0;
  if (b1 == 0x3F) return ((const uint16_t*)mp)[idx] != 0;
  return m8[idx] != 0;
}

// fp32 pred pipeline for current class c, reference op order, exp/log CR.
template <int D>
__device__ void fill_logp(const void* __restrict__ W, bool bf, float gamma,
                          int c, float* __restrict__ out) {
  float t[D];
  for (int d = 0; d < D; ++d) t[d] = ld(W, c * D + d, bf);
  float m = t[0];
  for (int d = 1; d < D; ++d) m = fmaxf(m, t[d]);
  float u[D];
  for (int d = 0; d < D; ++d) u[d] = expf_cr(t[d] - m);
  float s = 0.0f;
  for (int d = 0; d < D; ++d) s += u[d];
  float p[D];
  for (int d = 0; d < D; ++d) p[d] = (u[d] / s) * gamma;
  p[c] = 0.0f;
  float s1 = 0.0f;
  for (int d = 0; d < D; ++d) s1 += p[d];
  float r = fmaxf(1.0f - s1, 0.0f);
  p[c] = r;
  float s2 = 0.0f;
  for (int d = 0; d < D; ++d) s2 += p[d];
  for (int d = 0; d < D; ++d) out[d] = logf_cr(p[d] / s2);
}

__device__ __forceinline__ void pair_decode(int q, int& lo, int& hi) {
  lo = 0; int rem = q;
  while (rem >= 63 - lo) { rem -= 63 - lo; lo++; }
  hi = lo + 1 + rem;
}

// ---------------- K0: per-step PRNG subkeys + zero compaction counter ------
__global__ void key_kernel(uint8_t* __restrict__ ws) {
  int t = threadIdx.x;
  uint32_t* wk = (uint32_t*)(ws + WS_KEYS);
  if (t == 0) wk[200] = 0u;
  if (t < STEPS) {
    uint32_t f0, f1, a0, a1;
    tf2x32(0u, 42u, 0u, (uint32_t)t, f0, f1);
    tf2x32(f0, f1, 0u, 0u, a0, a1);  // kx
    wk[2 * t] = a0; wk[2 * t + 1] = a1;
    tf2x32(f0, f1, 0u, 1u, a0, a1);  // ke
    wk[100 + 2 * t] = a0; wk[101 + 2 * t] = a1;
  }
}

// ---------------- Kc: compact valid edge chains -> u16 list ----------------
__global__ __launch_bounds__(256) void compact_kernel(const void* __restrict__ M,
                                                      uint8_t* __restrict__ ws) {
  int chain = blockIdx.x * 256 + threadIdx.x;
  if (chain >= EDGE_CHAINS) return;
  int b = chain / NPAIR, q = chain % NPAIR, lo, hi;
  pair_decode(q, lo, hi);
  if (read_mask(M, b * NN + lo) && read_mask(M, b * NN + hi)) {
    uint32_t slot = atomicAdd((uint32_t*)(ws + WS_KEYS) + 200, 1u);
    ((uint16_t*)(ws + WS_CL))[slot] = (uint16_t)chain;
  }
}

// ---------------- K1: all gumbels, 4-way ILP per thread ----------------
__global__ __launch_bounds__(256) void gumbel_kernel(const void* __restrict__ M,
                                                     uint8_t* __restrict__ ws) {
  const uint32_t* keys = (const uint32_t*)(ws + WS_KEYS);
  float* ge = (float*)(ws + WS_GE);
  float* gn = (float*)(ws + WS_GN);
  int blk = blockIdx.x, tid = threadIdx.x;
  if (blk < EBLK) {
    uint32_t cnt = keys[200];
    if ((uint32_t)(blk * 4) >= cnt) return;
    if (tid >= STEPS * DEC) return;
    const uint16_t* cl = (const uint16_t*)(ws + WS_CL);
    int k = tid / DEC, d = tid % DEC;
    uint32_t kk0 = keys[100 + 2 * k], kk1 = keys[101 + 2 * k];
    int ch[4]; uint32_t ctr[4]; bool ok[4];
#pragma unroll
    for (int j = 0; j < 4; ++j) {
      uint32_t idx = (uint32_t)(blk * 4 + j);
      ok[j] = idx < cnt;
      int chain = cl[ok[j] ? idx : 0];
      ch[j] = chain;
      int b = chain / NPAIR, q = chain % NPAIR, lo, hi;
      pair_decode(q, lo, hi);
      ctr[j] = (uint32_t)(((b * NN + lo) * NN + hi) * DEC + d);
    }
    float v0 = gumbel_inl(kk0, kk1, ctr[0]);
    float v1 = gumbel_inl(kk0, kk1, ctr[1]);
    float v2 = gumbel_inl(kk0, kk1, ctr[2]);
    float v3 = gumbel_inl(kk0, kk1, ctr[3]);
    if (ok[0]) ge[(size_t)ch[0] * 250 + tid] = v0;
    if (ok[1]) ge[(size_t)ch[1] * 250 + tid] = v1;
    if (ok[2]) ge[(size_t)ch[2] * 250 + tid] = v2;
    if (ok[3]) ge[(size_t)ch[3] * 250 + tid] = v3;
  } else {
    int n0 = (blk - EBLK) * 4;  // 4 nodes per block
    bool ok[4];
#pragma unroll
    for (int j = 0; j < 4; ++j) ok[j] = read_mask(M, n0 + j);
    for (int r = 0; r < 2; ++r) {
      int slot = r * 256 + tid;
      if (slot < STEPS * DXC) {
        int k = slot >> 3, d = slot & 7;
        uint32_t kk0 = keys[2 * k], kk1 = keys[2 * k + 1];
        float w[4];
#pragma unroll
        for (int j = 0; j < 4; ++j)
          w[j] = gumbel_inl(kk0, kk1, (uint32_t)((n0 + j) * DXC + d));
#pragma unroll
        for (int j = 0; j < 4; ++j)
          if (ok[j]) gn[(size_t)(n0 + j) * 400 + slot] = w[j];
      }
    }
  }
}

// ---------------- K2: sequential argmax chains -> transposed sample bytes --
// blocks [0,252): edge chains (thread per canonical pair); [252,260): nodes.
__global__ __launch_bounds__(256) void chain_kernel(
    const void* __restrict__ X, const void* __restrict__ E,
    const void* __restrict__ M, const void* __restrict__ gammas,
    const void* __restrict__ Wx, const void* __restrict__ We,
    uint8_t* __restrict__ ws) {
  __shared__ float stab[STEPS * DXC * DXC];
  const bool edge_blk = blockIdx.x < 252;
  const int t = threadIdx.x;
  const bool bf = detect_bf16(X);

  if (edge_blk) {
    for (int task = t; task < STEPS * DEC; task += 256)
      fill_logp<DEC>(We, bf, ld(gammas, task / DEC, bf), task % DEC,
                     &stab[task * DEC]);
  } else {
    for (int task = t; task < STEPS * DXC; task += 256)
      fill_logp<DXC>(Wx, bf, ld(gammas, task / DXC, bf), task % DXC,
                     &stab[task * DXC]);
  }
  __syncthreads();

  if (edge_blk) {
    int chain = blockIdx.x * 256 + t;  // < 64512
    int b = chain / NPAIR, q = chain % NPAIR, lo, hi;
    pair_decode(q, lo, hi);
    if (!(read_mask(M, b * NN + lo) && read_mask(M, b * NN + hi))) return;
    size_t crow = (((size_t)(b * NN + lo)) * NN + hi) * DEC;
    int cur = 0;
    float bst = ld(E, crow, bf);
    for (int d = 1; d < DEC; ++d) {
      float v = ld(E, crow + d, bf);
      if (v > bst) { bst = v; cur = d; }
    }
    const float* g = (const float*)(ws + WS_GE) + (size_t)chain * 250;
    uint8_t* s2e = ws + WS_S2E;
    for (int k = 0; k < STEPS; ++k) {
      const float* le = stab + (k * DEC + cur) * DEC;
      const float* gk = g + k * DEC;
      float bs = -3.0e38f; int nxt = 0;
      for (int d = 0; d < DEC; ++d) {
        float s = le[d] + gk[d];
        if (s > bs) { bs = s; nxt = d; }  // first-max, like jnp.argmax
      }
      s2e[(size_t)(b * STEPS + k) * NPAIR + q] = (uint8_t)nxt;  // coalesced
      cur = nxt;
    }
  } else {
    int node = (int)(blockIdx.x - 252) * 256 + t;  // < 2048
    if (!read_mask(M, node)) return;
    int b = node >> 6, i = node & 63;
    int cur = 0;
    float bst = ld(X, (size_t)node * DXC, bf);
    for (int d = 1; d < DXC; ++d) {
      float v = ld(X, (size_t)node * DXC + d, bf);
      if (v > bst) { bst = v; cur = d; }
    }
    const float* g = (const float*)(ws + WS_GN) + (size_t)node * 400;
    uint8_t* s2n = ws + WS_S2N;
    for (int k = 0; k < STEPS; ++k) {
      const float* le = stab + (k * DXC + cur) * DXC;
      const float* gk = g + k * DXC;
      float bs = -3.0e38f; int nxt = 0;
      for (int d = 0; d < DXC; ++d) {
        float s = le[d] + gk[d];
        if (s > bs) { bs = s; nxt = d; }
      }
      s2n[(size_t)(b * STEPS + k) * 64 + i] = (uint8_t)nxt;  // coalesced
      cur = nxt;
    }
  }
}

// ---------------- K3: slab writer, float4 stores ----------------
// blocks [0,1600): edge slab (b,k); [1600,1632): node batch b (all k).
__global__ __launch_bounds__(256) void write_kernel(
    const void* __restrict__ X, const void* __restrict__ E,
    const void* __restrict__ M, const uint8_t* __restrict__ ws,
    void* __restrict__ out) {
  __shared__ uint8_t cur_g[4096];
  __shared__ uint8_t pre_g[4096];
  __shared__ uint8_t sc[NPAIR];
  __shared__ uint8_t sp_[NPAIR];
  __shared__ uint8_t sn[3200];
  __shared__ uint8_t vf[64];
  const bool bf = detect_bf16(X);
  const int t = threadIdx.x;

  if (blockIdx.x < 1600) {
    int slab = blockIdx.x;  // b*50+k
    int b = slab / STEPS, k = slab % STEPS;
    if (t < 64) vf[t] = read_mask(M, b * NN + t) ? 1 : 0;
    const uint8_t* s2e = ws + WS_S2E;
    for (int x = t; x < 504; x += 256) {
      ((uint32_t*)sc)[x] = ((const uint32_t*)(s2e + (size_t)slab * NPAIR))[x];
      if (k > 0)
        ((uint32_t*)sp_)[x] =
            ((const uint32_t*)(s2e + (size_t)(slab - 1) * NPAIR))[x];
    }
    __syncthreads();
    for (int ij = t; ij < 4096; ij += 256) {
      int i = ij >> 6, j = ij & 63;
      uint8_t c = 0xFF, p = 0xFF;
      if (i != j && vf[i] && vf[j]) {
        int lo = i < j ? i : j, hi = i < j ? j : i;
        int q = 63 * lo - ((lo * (lo - 1)) >> 1) + hi - lo - 1;
        c = sc[q];
        if (k > 0) p = sp_[q];
      }
      cur_g[ij] = c; pre_g[ij] = p;
    }
    __syncthreads();
    size_t base = (size_t)slab * 20480;
    // out1 (post-sample En)
    for (int f = t; f < 5120; f += 256) {
      int e0 = f * 4;
      float v[4];
#pragma unroll
      for (int m = 0; m < 4; ++m) {
        int e = e0 + m, ij = e / 5, d = e - ij * 5;
        v[m] = (d == (int)cur_g[ij]) ? 1.0f : 0.0f;
      }
      stv4(out, (OFF_TOTE + base) / 4 + f, bf, v[0], v[1], v[2], v[3]);
    }
    // out3 (pre-state Ec)
    if (k == 0) {
      size_t src4 = (size_t)b * 5120;
      for (int f = t; f < 5120; f += 256)
        cpy4(out, E, (OFF_OUTE + base) / 4 + f, src4 + f, bf);
    } else {
      for (int f = t; f < 5120; f += 256) {
        int e0 = f * 4;
        float v[4];
#pragma unroll
        for (int m = 0; m < 4; ++m) {
          int e = e0 + m, ij = e / 5, d = e - ij * 5;
          v[m] = (d == (int)pre_g[ij]) ? 1.0f : 0.0f;
        }
        stv4(out, (OFF_OUTE + base) / 4 + f, bf, v[0], v[1], v[2], v[3]);
      }
    }
  } else {
    int b = (int)blockIdx.x - 1600;  // 0..31
    if (t < 64) vf[t] = read_mask(M, b * NN + t) ? 1 : 0;
    for (int x = t; x < 800; x += 256)
      ((uint32_t*)sn)[x] =
          ((const uint32_t*)(ws + WS_S2N + (size_t)b * STEPS * 64))[x];
    __syncthreads();
    size_t base0 = (size_t)b * 25600;  // elements, out0
    // out0 (post-sample Xn), 6400 float4
    for (int f = t; f < 6400; f += 256) {
      int e0 = f * 4;
      int k = e0 >> 9, i = (e0 >> 3) & 63;  // same k,i for all 4 elems
      int s = (int)sn[k * 64 + i];
      bool va = vf[i] != 0;
      float v[4];
#pragma unroll
      for (int m = 0; m < 4; ++m) {
        int d = (e0 + m) & 7;
        v[m] = (va && d == s) ? 1.0f : 0.0f;
      }
      stv4(out, base0 / 4 + f, bf, v[0], v[1], v[2], v[3]);
    }
    // out2 (pre-state Xc)
    for (int f = t; f < 6400; f += 256) {
      int e0 = f * 4;
      int k = e0 >> 9, i = (e0 >> 3) & 63;
      if (k == 0) {
        cpy4(out, X, (OFF_OUTX + base0) / 4 + f,
             ((size_t)b * 512 + (size_t)(e0 & 511)) / 4, bf);
      } else {
        int s = (int)sn[(k - 1) * 64 + i];
        bool va = vf[i] != 0;
        float v[4];
#pragma unroll
        for (int m = 0; m < 4; ++m) {
          int d = (e0 + m) & 7;
          v[m] = (va && d == s) ? 1.0f : 0.0f;
        }
        stv4(out, (OFF_OUTX + base0) / 4 + f, bf, v[0], v[1], v[2], v[3]);
      }
    }
  }
}

// ---------------- fallback: r8's passing single kernel ----------------
__global__ __launch_bounds__(256) void lang_kernel(
    const void* __restrict__ X, const void* __restrict__ E,
    const void* __restrict__ M, const void* __restrict__ gammas,
    const void* __restrict__ Wx, const void* __restrict__ We,
    void* __restrict__ out) {
  __shared__ uint32_t skeys[STEPS * 2];
  __shared__ float stab[STEPS * DXC * DXC];
  const bool edge_blk = blockIdx.x < 512;
  const int t = threadIdx.x;
  const bool bf = detect_bf16(X);

  if (t < STEPS) {
    uint32_t f0, f1, a0, a1;
    tf2x32(0u, 42u, 0u, (uint32_t)t, f0, f1);
    tf2x32(f0, f1, 0u, edge_blk ? 1u : 0u, a0, a1);
    skeys[2 * t] = a0; skeys[2 * t + 1] = a1;
  }
  if (edge_blk) {
    for (int task = t; task < STEPS * DEC; task += 256) {
      int k = task / DEC, c = task % DEC;
      fill_logp<DEC>(We, bf, ld(gammas, k, bf), c, &stab[(k * DEC + c) * DEC]);
    }
  } else {
    for (int task = t; task < STEPS * DXC; task += 256) {
      int k = task / DXC, c = task % DXC;
      fill_logp<DXC>(Wx, bf, ld(gammas, k, bf), c, &stab[(k * DXC + c) * DXC]);
    }
  }
  __syncthreads();

  if (edge_blk) {
    int tid = blockIdx.x * 256 + threadIdx.x;
    int b = tid >> 12, rem = tid & 4095, i = rem >> 6, j = rem & 63;
    bool valid = (i != j) && read_mask(M, b * NN + i) && read_mask(M, b * NN + j);
    int lo = i < j ? i : j, hi = i < j ? j : i;
    int cur = 0;
    if (valid) {
      size_t crow = (((size_t)(b * NN + lo)) * NN + hi) * DEC;
      float bst = ld(E, crow, bf);
      for (int d = 1; d < DEC; ++d) {
        float v = ld(E, crow + d, bf);
        if (v > bst) { bst = v; cur = d; }
      }
    }
    uint32_t base = (uint32_t)((((b * NN) + lo) * NN + hi) * DEC);
#pragma clang loop unroll(disable)
    for (int k = 0; k < STEPS; ++k) {
      size_t tp = ((((size_t)b * STEPS + k) * NN + i) * NN + j) * DEC;
      if (k == 0) {
        for (int d = 0; d < DEC; ++d)
          st(out, OFF_OUTE + tp + d, bf, ld(E, (size_t)tid * DEC + d, bf));
      } else {
        for (int d = 0; d < DEC; ++d)
          st(out, OFF_OUTE + tp + d, bf, (valid && d == cur) ? 1.0f : 0.0f);
      }
      int nxt = 0;
      if (valid) {
        const float* le = stab + (k * DEC + cur) * DEC;
        uint32_t k0 = skeys[2 * k], k1 = skeys[2 * k + 1];
        float bst = -3.0e38f;
        for (int d = 0; d < DEC; ++d) {
          float s = le[d] + gumbel_part(k0, k1, base + (uint32_t)d);
          if (s > bst) { bst = s; nxt = d; }
        }
      }
      for (int d = 0; d < DEC; ++d)
        st(out, OFF_TOTE + tp + d, bf, (valid && d == nxt) ? 1.0f : 0.0f);
      cur = nxt;
    }
  } else {
    int tid = (int)(blockIdx.x - 512) * 256 + threadIdx.x;
    if (tid >= BSZ * NN) return;
    int b = tid >> 6, i = tid & 63;
    bool valid = read_mask(M, tid);
    int cur = 0;
    {
      float bst = ld(X, (size_t)tid * DXC, bf);
      for (int d = 1; d < DXC; ++d) {
        float v = ld(X, (size_t)tid * DXC + d, bf);
        if (v > bst) { bst = v; cur = d; }
      }
    }
    uint32_t base = (uint32_t)(tid * DXC);
#pragma clang loop unroll(disable)
    for (int k = 0; k < STEPS; ++k) {
      size_t tp = (((size_t)b * STEPS + k) * NN + i) * DXC;
      if (k == 0) {
        for (int d = 0; d < DXC; ++d)
          st(out, OFF_OUTX + tp + d, bf, ld(X, (size_t)tid * DXC + d, bf));
      } else {
        for (int d = 0; d < DXC; ++d)
          st(out, OFF_OUTX + tp + d, bf, (valid && d == cur) ? 1.0f : 0.0f);
      }
      int nxt = 0;
      if (valid) {
        const float* lx = stab + (k * DXC + cur) * DXC;
        uint32_t k0 = skeys[2 * k], k1 = skeys[2 * k + 1];
        float bst = -3.0e38f;
        for (int d = 0; d < DXC; ++d) {
          float s = lx[d] + gumbel_part(k0, k1, base + (uint32_t)d);
          if (s > bst) { bst = s; nxt = d; }
        }
      }
      for (int d = 0; d < DXC; ++d)
        st(out, tp + d, bf, (valid && d == nxt) ? 1.0f : 0.0f);
      cur = nxt;
    }
  }
}

extern "C" void kernel_launch(void* const* d_in, const int* in_sizes, int n_in,
                              void* d_out, int out_size, void* d_ws, size_t ws_size,
                              hipStream_t stream) {
  (void)out_size;
  const void* X = d_in[0];
  const void* E = d_in[1];
  const void* M = d_in[2];
  const void* G = d_in[3];
  const void* Wx = d_in[4];
  const void* We = d_in[5];
  for (int i = 0; i < n_in && i < 6; ++i) {
    switch (in_sizes[i]) {
      case 16384:  X = d_in[i]; break;
      case 655360: E = d_in[i]; break;
      case 2048:   M = d_in[i]; break;
      case 50:     G = d_in[i]; break;
      case 64:     Wx = d_in[i]; break;
      case 25:     We = d_in[i]; break;
      default: break;
    }
  }
  if (ws_size >= WS_NEED) {
    uint8_t* ws = (uint8_t*)d_ws;
    hipLaunchKernelGGL(key_kernel, dim3(1), dim3(64), 0, stream, ws);
    hipLaunchKernelGGL(compact_kernel, dim3(252), dim3(256), 0, stream, M, ws);
    hipLaunchKernelGGL(gumbel_kernel, dim3(EBLK + 512), dim3(256), 0, stream,
                       M, ws);
    hipLaunchKernelGGL(chain_kernel, dim3(260), dim3(256), 0, stream,
                       X, E, M, G, Wx, We, ws);
    hipLaunchKernelGGL(write_kernel, dim3(1632), dim3(256), 0, stream,
                       X, E, M, ws, d_out);
  } else {
    hipLaunchKernelGGL(lang_kernel, dim3(520), dim3(256), 0, stream,
                       X, E, M, G, Wx, We, d_out);
  }
}

// Round 11
// 433.195 us; speedup vs baseline: 1.6476x; 1.0072x over previous
//
#include <hip/hip_runtime.h>
#include <stdint.h>

#pragma clang fp contract(off)

#define STEPS 50
#define BSZ 32
#define NN 64
#define DXC 8
#define DEC 5
// Output order (scan-unpack): out0=stacked Xn, out1=stacked En,
// out2=stacked Xc, out3=stacked Ec.
#define OFF_TOTE 819200UL     // out1 base (elements)
#define OFF_OUTX 33587200UL   // out2 base
#define OFF_OUTE 34406400UL   // out3 base

#define NPAIR 2016            // upper-tri pairs per batch
#define EDGE_CHAINS 64512     // 32*2016
// ws layout (bytes); ws is 1 GiB (r10 fill evidence), need ~71.5 MB
#define WS_KEYS 0UL                 // u32[256]: kx[0..99], ke[100..199], cnt[200]
#define WS_CL   1024UL              // u16[64512] compacted chain ids
#define WS_CB   130048UL            // u32[64512] chain counter-base (=crow)
#define WS_GE   388096UL            // f32[250][64512] slab-major gumbels
#define WS_GN   64900096UL          // f32[400][2048] slab-major node gumbels
#define WS_S2E  68176896UL          // u8[1600][2016] samples, slab-major
#define WS_S2N  71402496UL          // u8[1600][64]
#define WS_NEED 71504896UL

// ---------------- threefry2x32 (JAX-exact, 20 rounds) ----------------
__device__ __forceinline__ uint32_t rotl32(uint32_t x, int d) {
  return (x << d) | (x >> (32 - d));
}

__device__ __forceinline__ void tf2x32(uint32_t k0, uint32_t k1,
                                       uint32_t x0, uint32_t x1,
                                       uint32_t& o0, uint32_t& o1) {
  uint32_t ks2 = k0 ^ k1 ^ 0x1BD11BDAu;
  x0 += k0; x1 += k1;
#define TF_R(r) { x0 += x1; x1 = rotl32(x1, (r)); x1 ^= x0; }
  TF_R(13) TF_R(15) TF_R(26) TF_R(6)
  x0 += k1; x1 += ks2 + 1u;
  TF_R(17) TF_R(29) TF_R(16) TF_R(24)
  x0 += ks2; x1 += k0 + 2u;
  TF_R(13) TF_R(15) TF_R(26) TF_R(6)
  x0 += k0; x1 += k1 + 3u;
  TF_R(17) TF_R(29) TF_R(16) TF_R(24)
  x0 += k1; x1 += ks2 + 4u;
  TF_R(13) TF_R(15) TF_R(26) TF_R(6)
  x0 += ks2; x1 += k0 + 5u;
#undef TF_R
  o0 = x0; o1 = x1;
}

__device__ __forceinline__ float logf_cr(float x) { return (float)log((double)x); }
__device__ __forceinline__ float expf_cr(float x) { return (float)exp((double)x); }

// JAX PARTITIONABLE random_bits: bits[i] = o0 ^ o1 of cipher(key, (hi=0, lo=i));
// uniform(tiny,1) == max(uf, tiny) bit-exactly; gumbel = -log(-log(u)) fp32 CR.
__device__ __forceinline__ float gumbel_inl(uint32_t k0, uint32_t k1,
                                            uint32_t idx) {
  uint32_t o0, o1;
  tf2x32(k0, k1, 0u, idx, o0, o1);
  uint32_t bits = o0 ^ o1;
  float uf = __uint_as_float((bits >> 9) | 0x3f800000u) - 1.0f;
  float u = fmaxf(uf, 1.1754943508222875e-38f);
  return -logf_cr(-logf_cr(u));
}
__device__ __attribute__((noinline)) float gumbel_part(uint32_t k0, uint32_t k1,
                                                       uint32_t idx) {
  return gumbel_inl(k0, k1, idx);
}

// dtype auto-detect on X's first 32 bytes.
__device__ __forceinline__ bool detect_bf16(const void* X) {
  const uint16_t* u = (const uint16_t*)X;
  int c = 0;
  for (int i = 0; i < 16; ++i) c += (u[i] == 0x3F80u);
  return c >= 2;
}

__device__ __forceinline__ float ld(const void* p, size_t i, bool bf) {
  if (bf) return __uint_as_float(((uint32_t)((const uint16_t*)p)[i]) << 16);
  return ((const float*)p)[i];
}
__device__ __forceinline__ void st(void* p, size_t i, bool bf, float v) {
  if (bf) ((uint16_t*)p)[i] = (uint16_t)(__float_as_uint(v) >> 16);
  else ((float*)p)[i] = v;
}
__device__ __forceinline__ void stv4(void* p, size_t e4, bool bf,
                                     float a, float b, float c, float d) {
  if (!bf) {
    float4 v; v.x = a; v.y = b; v.z = c; v.w = d;
    ((float4*)p)[e4] = v;
  } else {
    ushort4 v;
    v.x = (uint16_t)(__float_as_uint(a) >> 16);
    v.y = (uint16_t)(__float_as_uint(b) >> 16);
    v.z = (uint16_t)(__float_as_uint(c) >> 16);
    v.w = (uint16_t)(__float_as_uint(d) >> 16);
    ((ushort4*)p)[e4] = v;
  }
}
__device__ __forceinline__ void cpy4(void* dst, const void* src, size_t de4,
                                     size_t se4, bool bf) {
  if (!bf) ((float4*)dst)[de4] = ((const float4*)src)[se4];
  else ((uint2*)dst)[de4] = ((const uint2*)src)[se4];
}

__device__ __forceinline__ bool read_mask(const void* mp, int idx) {
  const uint8_t* m8 = (const uint8_t*)mp;
  uint8_t b1 = m8[1];
  if (b1 == 0) return ((const uint32_t*)mp)[idx] != 0;
  if (b1 == 0x3F) return ((const uint16_t*)mp)[idx] != 0;
  return m8[idx] != 0;
}

// fp32 pred pipeline for current class c, reference op order, exp/log CR.
template <int D>
__device__ void fill_logp(const void* __restrict__ W, bool bf, float gamma,
                          int c, float* __restrict__ out) {
  float t[D];
  for (int d = 0; d < D; ++d) t[d] = ld(W, c * D + d, bf);
  float m = t[0];
  for (int d = 1; d < D; ++d) m = fmaxf(m, t[d]);
  float u[D];
  for (int d = 0; d < D; ++d) u[d] = expf_cr(t[d] - m);
  float s = 0.0f;
  for (int d = 0; d < D; ++d) s += u[d];
  float p[D];
  for (int d = 0; d < D; ++d) p[d] = (u[d] / s) * gamma;
  p[c] = 0.0f;
  float s1 = 0.0f;
  for (int d = 0; d < D; ++d) s1 += p[d];
  float r = fmaxf(1.0f - s1, 0.0f);
  p[c] = r;
  float s2 = 0.0f;
  for (int d = 0; d < D; ++d) s2 += p[d];
  for (int d = 0; d < D; ++d) out[d] = logf_cr(p[d] / s2);
}

__device__ __forceinline__ void pair_decode(int q, int& lo, int& hi) {
  lo = 0; int rem = q;
  while (rem >= 63 - lo) { rem -= 63 - lo; lo++; }
  hi = lo + 1 + rem;
}

// ---------------- K0: per-step PRNG subkeys + zero compaction counter ------
__global__ void key_kernel(uint8_t* __restrict__ ws) {
  int t = threadIdx.x;
  uint32_t* wk = (uint32_t*)(ws + WS_KEYS);
  if (t == 0) wk[200] = 0u;
  if (t < STEPS) {
    uint32_t f0, f1, a0, a1;
    tf2x32(0u, 42u, 0u, (uint32_t)t, f0, f1);
    tf2x32(f0, f1, 0u, 0u, a0, a1);  // kx
    wk[2 * t] = a0; wk[2 * t + 1] = a1;
    tf2x32(f0, f1, 0u, 1u, a0, a1);  // ke
    wk[100 + 2 * t] = a0; wk[101 + 2 * t] = a1;
  }
}

// ---------------- Kc: compact valid edge chains -> ids + counter bases -----
__global__ __launch_bounds__(256) void compact_kernel(const void* __restrict__ M,
                                                      uint8_t* __restrict__ ws) {
  int chain = blockIdx.x * 256 + threadIdx.x;
  if (chain >= EDGE_CHAINS) return;
  int b = chain / NPAIR, q = chain % NPAIR, lo, hi;
  pair_decode(q, lo, hi);
  if (read_mask(M, b * NN + lo) && read_mask(M, b * NN + hi)) {
    uint32_t slot = atomicAdd((uint32_t*)(ws + WS_KEYS) + 200, 1u);
    ((uint16_t*)(ws + WS_CL))[slot] = (uint16_t)chain;
    ((uint32_t*)(ws + WS_CB))[slot] =
        (uint32_t)(((b * NN + lo) * NN + hi) * DEC);
  }
}

// ---------------- K1: all gumbels, fully coalesced slab-major ----------------
// grid (252, 263): y<250 -> edge slab y=(k*5+d), thread per compacted slot;
// y>=250 -> node work: idx=(y-250)*252+bx < 3200, slab=idx>>3=(k*8+d).
__global__ __launch_bounds__(256) void gumbel_kernel(const void* __restrict__ M,
                                                     uint8_t* __restrict__ ws) {
  const uint32_t* keys = (const uint32_t*)(ws + WS_KEYS);
  const int tid = threadIdx.x;
  if (blockIdx.y < 250) {
    uint32_t cnt = keys[200];
    uint32_t slot = blockIdx.x * 256 + tid;
    if (slot >= cnt) return;
    int slab = blockIdx.y, k = slab / DEC, d = slab - k * DEC;
    uint32_t ctr = ((const uint32_t*)(ws + WS_CB))[slot] + (uint32_t)d;
    ((float*)(ws + WS_GE))[(size_t)slab * EDGE_CHAINS + slot] =
        gumbel_inl(keys[100 + 2 * k], keys[101 + 2 * k], ctr);
  } else {
    int idx = ((int)blockIdx.y - 250) * 252 + (int)blockIdx.x;
    if (idx >= 3200) return;
    int slab = idx >> 3;               // 0..399 = k*8+d
    int node = ((idx & 7) << 8) + tid; // 0..2047
    if (!read_mask(M, node)) return;
    int k = slab >> 3, d = slab & 7;
    ((float*)(ws + WS_GN))[(size_t)slab * 2048 + node] =
        gumbel_inl(keys[2 * k], keys[2 * k + 1], (uint32_t)(node * DXC + d));
  }
}

// ---------------- K2: sequential argmax chains -> transposed sample bytes --
// blocks [0,252): edge chains (thread per compacted slot); [252,260): nodes.
__global__ __launch_bounds__(256) void chain_kernel(
    const void* __restrict__ X, const void* __restrict__ E,
    const void* __restrict__ M, const void* __restrict__ gammas,
    const void* __restrict__ Wx, const void* __restrict__ We,
    uint8_t* __restrict__ ws) {
  __shared__ float stab[STEPS * DXC * DXC];
  const bool edge_blk = blockIdx.x < 252;
  const int t = threadIdx.x;
  const bool bf = detect_bf16(X);

  if (edge_blk) {
    for (int task = t; task < STEPS * DEC; task += 256)
      fill_logp<DEC>(We, bf, ld(gammas, task / DEC, bf), task % DEC,
                     &stab[task * DEC]);
  } else {
    for (int task = t; task < STEPS * DXC; task += 256)
      fill_logp<DXC>(Wx, bf, ld(gammas, task / DXC, bf), task % DXC,
                     &stab[task * DXC]);
  }
  __syncthreads();

  if (edge_blk) {
    uint32_t cnt = ((const uint32_t*)(ws + WS_KEYS))[200];
    uint32_t slot = blockIdx.x * 256 + t;
    if (slot >= cnt) return;
    int chain = (int)((const uint16_t*)(ws + WS_CL))[slot];
    int b = chain / NPAIR, q = chain - b * NPAIR;
    uint32_t crow = ((const uint32_t*)(ws + WS_CB))[slot];
    int cur = 0;
    float bst = ld(E, crow, bf);
    for (int d = 1; d < DEC; ++d) {
      float v = ld(E, (size_t)crow + d, bf);
      if (v > bst) { bst = v; cur = d; }
    }
    const float* ge = (const float*)(ws + WS_GE);
    uint8_t* s2e = ws + WS_S2E;
    for (int k = 0; k < STEPS; ++k) {
      const float* le = stab + (k * DEC + cur) * DEC;
      float bs = -3.0e38f; int nxt = 0;
      for (int d = 0; d < DEC; ++d) {
        float s = le[d] + ge[(size_t)(k * DEC + d) * EDGE_CHAINS + slot];
        if (s > bs) { bs = s; nxt = d; }  // first-max, like jnp.argmax
      }
      s2e[(size_t)(b * STEPS + k) * NPAIR + q] = (uint8_t)nxt;
      cur = nxt;
    }
  } else {
    int node = (int)(blockIdx.x - 252) * 256 + t;  // < 2048
    if (!read_mask(M, node)) return;
    int b = node >> 6, i = node & 63;
    int cur = 0;
    float bst = ld(X, (size_t)node * DXC, bf);
    for (int d = 1; d < DXC; ++d) {
      float v = ld(X, (size_t)node * DXC + d, bf);
      if (v > bst) { bst = v; cur = d; }
    }
    const float* gn = (const float*)(ws + WS_GN);
    uint8_t* s2n = ws + WS_S2N;
    for (int k = 0; k < STEPS; ++k) {
      const float* le = stab + (k * DXC + cur) * DXC;
      float bs = -3.0e38f; int nxt = 0;
      for (int d = 0; d < DXC; ++d) {
        float s = le[d] + gn[(size_t)(k * DXC + d) * 2048 + node];
        if (s > bs) { bs = s; nxt = d; }
      }
      s2n[(size_t)(b * STEPS + k) * 64 + i] = (uint8_t)nxt;
      cur = nxt;
    }
  }
}

// ---------------- K3: slab writer, float4 stores ----------------
// blocks [0,1600): edge slab (b,k); [1600,1632): node batch b (all k).
__global__ __launch_bounds__(256) void write_kernel(
    const void* __restrict__ X, const void* __restrict__ E,
    const void* __restrict__ M, const uint8_t* __restrict__ ws,
    void* __restrict__ out) {
  __shared__ uint8_t cur_g[4096];
  __shared__ uint8_t pre_g[4096];
  __shared__ uint8_t sc[NPAIR];
  __shared__ uint8_t sp_[NPAIR];
  __shared__ uint8_t sn[3200];
  __shared__ uint8_t vf[64];
  const bool bf = detect_bf16(X);
  const int t = threadIdx.x;

  if (blockIdx.x < 1600) {
    int slab = blockIdx.x;  // b*50+k
    int b = slab / STEPS, k = slab % STEPS;
    if (t < 64) vf[t] = read_mask(M, b * NN + t) ? 1 : 0;
    const uint8_t* s2e = ws + WS_S2E;
    for (int x = t; x < 504; x += 256) {
      ((uint32_t*)sc)[x] = ((const uint32_t*)(s2e + (size_t)slab * NPAIR))[x];
      if (k > 0)
        ((uint32_t*)sp_)[x] =
            ((const uint32_t*)(s2e + (size_t)(slab - 1) * NPAIR))[x];
    }
    __syncthreads();
    for (int ij = t; ij < 4096; ij += 256) {
      int i = ij >> 6, j = ij & 63;
      uint8_t c = 0xFF, p = 0xFF;
      if (i != j && vf[i] && vf[j]) {
        int lo = i < j ? i : j, hi = i < j ? j : i;
        int q = 63 * lo - ((lo * (lo - 1)) >> 1) + hi - lo - 1;
        c = sc[q];
        if (k > 0) p = sp_[q];
      }
      cur_g[ij] = c; pre_g[ij] = p;
    }
    __syncthreads();
    size_t base = (size_t)slab * 20480;
    for (int f = t; f < 5120; f += 256) {
      int e0 = f * 4;
      float v[4];
#pragma unroll
      for (int m = 0; m < 4; ++m) {
        int e = e0 + m, ij = e / 5, d = e - ij * 5;
        v[m] = (d == (int)cur_g[ij]) ? 1.0f : 0.0f;
      }
      stv4(out, (OFF_TOTE + base) / 4 + f, bf, v[0], v[1], v[2], v[3]);
    }
    if (k == 0) {
      size_t src4 = (size_t)b * 5120;
      for (int f = t; f < 5120; f += 256)
        cpy4(out, E, (OFF_OUTE + base) / 4 + f, src4 + f, bf);
    } else {
      for (int f = t; f < 5120; f += 256) {
        int e0 = f * 4;
        float v[4];
#pragma unroll
        for (int m = 0; m < 4; ++m) {
          int e = e0 + m, ij = e / 5, d = e - ij * 5;
          v[m] = (d == (int)pre_g[ij]) ? 1.0f : 0.0f;
        }
        stv4(out, (OFF_OUTE + base) / 4 + f, bf, v[0], v[1], v[2], v[3]);
      }
    }
  } else {
    int b = (int)blockIdx.x - 1600;  // 0..31
    if (t < 64) vf[t] = read_mask(M, b * NN + t) ? 1 : 0;
    for (int x = t; x < 800; x += 256)
      ((uint32_t*)sn)[x] =
          ((const uint32_t*)(ws + WS_S2N + (size_t)b * STEPS * 64))[x];
    __syncthreads();
    size_t base0 = (size_t)b * 25600;
    for (int f = t; f < 6400; f += 256) {
      int e0 = f * 4;
      int k = e0 >> 9, i = (e0 >> 3) & 63;
      int s = (int)sn[k * 64 + i];
      bool va = vf[i] != 0;
      float v[4];
#pragma unroll
      for (int m = 0; m < 4; ++m) {
        int d = (e0 + m) & 7;
        v[m] = (va && d == s) ? 1.0f : 0.0f;
      }
      stv4(out, base0 / 4 + f, bf, v[0], v[1], v[2], v[3]);
    }
    for (int f = t; f < 6400; f += 256) {
      int e0 = f * 4;
      int k = e0 >> 9, i = (e0 >> 3) & 63;
      if (k == 0) {
        cpy4(out, X, (OFF_OUTX + base0) / 4 + f,
             ((size_t)b * 512 + (size_t)(e0 & 511)) / 4, bf);
      } else {
        int s = (int)sn[(k - 1) * 64 + i];
        bool va = vf[i] != 0;
        float v[4];
#pragma unroll
        for (int m = 0; m < 4; ++m) {
          int d = (e0 + m) & 7;
          v[m] = (va && d == s) ? 1.0f : 0.0f;
        }
        stv4(out, (OFF_OUTX + base0) / 4 + f, bf, v[0], v[1], v[2], v[3]);
      }
    }
  }
}

// ---------------- fallback: r8's passing single kernel ----------------
__global__ __launch_bounds__(256) void lang_kernel(
    const void* __restrict__ X, const void* __restrict__ E,
    const void* __restrict__ M, const void* __restrict__ gammas,
    const void* __restrict__ Wx, const void* __restrict__ We,
    void* __restrict__ out) {
  __shared__ uint32_t skeys[STEPS * 2];
  __shared__ float stab[STEPS * DXC * DXC];
  const bool edge_blk = blockIdx.x < 512;
  const int t = threadIdx.x;
  const bool bf = detect_bf16(X);

  if (t < STEPS) {
    uint32_t f0, f1, a0, a1;
    tf2x32(0u, 42u, 0u, (uint32_t)t, f0, f1);
    tf2x32(f0, f1, 0u, edge_blk ? 1u : 0u, a0, a1);
    skeys[2 * t] = a0; skeys[2 * t + 1] = a1;
  }
  if (edge_blk) {
    for (int task = t; task < STEPS * DEC; task += 256) {
      int k = task / DEC, c = task % DEC;
      fill_logp<DEC>(We, bf, ld(gammas, k, bf), c, &stab[(k * DEC + c) * DEC]);
    }
  } else {
    for (int task = t; task < STEPS * DXC; task += 256) {
      int k = task / DXC, c = task % DXC;
      fill_logp<DXC>(Wx, bf, ld(gammas, k, bf), c, &stab[(k * DXC + c) * DXC]);
    }
  }
  __syncthreads();

  if (edge_blk) {
    int tid = blockIdx.x * 256 + threadIdx.x;
    int b = tid >> 12, rem = tid & 4095, i = rem >> 6, j = rem & 63;
    bool valid = (i != j) && read_mask(M, b * NN + i) && read_mask(M, b * NN + j);
    int lo = i < j ? i : j, hi = i < j ? j : i;
    int cur = 0;
    if (valid) {
      size_t crow = (((size_t)(b * NN + lo)) * NN + hi) * DEC;
      float bst = ld(E, crow, bf);
      for (int d = 1; d < DEC; ++d) {
        float v = ld(E, crow + d, bf);
        if (v > bst) { bst = v; cur = d; }
      }
    }
    uint32_t base = (uint32_t)((((b * NN) + lo) * NN + hi) * DEC);
#pragma clang loop unroll(disable)
    for (int k = 0; k < STEPS; ++k) {
      size_t tp = ((((size_t)b * STEPS + k) * NN + i) * NN + j) * DEC;
      if (k == 0) {
        for (int d = 0; d < DEC; ++d)
          st(out, OFF_OUTE + tp + d, bf, ld(E, (size_t)tid * DEC + d, bf));
      } else {
        for (int d = 0; d < DEC; ++d)
          st(out, OFF_OUTE + tp + d, bf, (valid && d == cur) ? 1.0f : 0.0f);
      }
      int nxt = 0;
      if (valid) {
        const float* le = stab + (k * DEC + cur) * DEC;
        uint32_t k0 = skeys[2 * k], k1 = skeys[2 * k + 1];
        float bst = -3.0e38f;
        for (int d = 0; d < DEC; ++d) {
          float s = le[d] + gumbel_part(k0, k1, base + (uint32_t)d);
          if (s > bst) { bst = s; nxt = d; }
        }
      }
      for (int d = 0; d < DEC; ++d)
        st(out, OFF_TOTE + tp + d, bf, (valid && d == nxt) ? 1.0f : 0.0f);
      cur = nxt;
    }
  } else {
    int tid = (int)(blockIdx.x - 512) * 256 + threadIdx.x;
    if (tid >= BSZ * NN) return;
    int b = tid >> 6, i = tid & 63;
    bool valid = read_mask(M, tid);
    int cur = 0;
    {
      float bst = ld(X, (size_t)tid * DXC, bf);
      for (int d = 1; d < DXC; ++d) {
        float v = ld(X, (size_t)tid * DXC + d, bf);
        if (v > bst) { bst = v; cur = d; }
      }
    }
    uint32_t base = (uint32_t)(tid * DXC);
#pragma clang loop unroll(disable)
    for (int k = 0; k < STEPS; ++k) {
      size_t tp = (((size_t)b * STEPS + k) * NN + i) * DXC;
      if (k == 0) {
        for (int d = 0; d < DXC; ++d)
          st(out, OFF_OUTX + tp + d, bf, ld(X, (size_t)tid * DXC + d, bf));
      } else {
        for (int d = 0; d < DXC; ++d)
          st(out, OFF_OUTX + tp + d, bf, (valid && d == cur) ? 1.0f : 0.0f);
      }
      int nxt = 0;
      if (valid) {
        const float* lx = stab + (k * DXC + cur) * DXC;
        uint32_t k0 = skeys[2 * k], k1 = skeys[2 * k + 1];
        float bst = -3.0e38f;
        for (int d = 0; d < DXC; ++d) {
          float s = lx[d] + gumbel_part(k0, k1, base + (uint32_t)d);
          if (s > bst) { bst = s; nxt = d; }
        }
      }
      for (int d = 0; d < DXC; ++d)
        st(out, tp + d, bf, (valid && d == nxt) ? 1.0f : 0.0f);
      cur = nxt;
    }
  }
}

extern "C" void kernel_launch(void* const* d_in, const int* in_sizes, int n_in,
                              void* d_out, int out_size, void* d_ws, size_t ws_size,
                              hipStream_t stream) {
  (void)out_size;
  const void* X = d_in[0];
  const void* E = d_in[1];
  const void* M = d_in[2];
  const void* G = d_in[3];
  const void* Wx = d_in[4];
  const void* We = d_in[5];
  for (int i = 0; i < n_in && i < 6; ++i) {
    switch (in_sizes[i]) {
      case 16384:  X = d_in[i]; break;
      case 655360: E = d_in[i]; break;
      case 2048:   M = d_in[i]; break;
      case 50:     G = d_in[i]; break;
      case 64:     Wx = d_in[i]; break;
      case 25:     We = d_in[i]; break;
      default: break;
    }
  }
  if (ws_size >= WS_NEED) {
    uint8_t* ws = (uint8_t*)d_ws;
    hipLaunchKernelGGL(key_kernel, dim3(1), dim3(64), 0, stream, ws);
    hipLaunchKernelGGL(compact_kernel, dim3(252), dim3(256), 0, stream, M, ws);
    hipLaunchKernelGGL(gumbel_kernel, dim3(252, 263), dim3(256), 0, stream,
                       M, ws);
    hipLaunchKernelGGL(chain_kernel, dim3(260), dim3(256), 0, stream,
                       X, E, M, G, Wx, We, ws);
    hipLaunchKernelGGL(write_kernel, dim3(1632), dim3(256), 0, stream,
                       X, E, M, ws, d_out);
  } else {
    hipLaunchKernelGGL(lang_kernel, dim3(520), dim3(256), 0, stream,
                       X, E, M, G, Wx, We, d_out);
  }
}